// Round 7
// baseline (669.343 us; speedup 1.0000x reference)
//
#include <hip/hip_runtime.h>
#include <stdint.h>

// Problem constants
#define B_    8
#define CIN   1024
#define H_    64
#define W_    48
#define OC    512
#define HW    3072          // H*W
#define NPOS  24576         // B*H*W
#define K9    9216          // 9*CIN
#define HP    66            // H+2
#define WP    50            // W+2

typedef __attribute__((ext_vector_type(8))) __bf16 bf16x8;
typedef __attribute__((ext_vector_type(4))) float  float4_t;
typedef __attribute__((ext_vector_type(4))) unsigned short ushort4_t;
typedef __attribute__((ext_vector_type(8))) int int8v;
typedef __attribute__((ext_vector_type(4))) int int4v;

__device__ __forceinline__ unsigned short f2bf(float x) {
  union { float f; unsigned u; } v; v.f = x;
  unsigned r = v.u + 0x7FFFu + ((v.u >> 16) & 1u);
  return (unsigned short)(r >> 16);
}

// pack 4 floats -> 4 fp8 e4m3 bytes (RNE, saturating)
__device__ __forceinline__ unsigned int pack4_fp8(float a, float b, float c, float d) {
  int w = __builtin_amdgcn_cvt_pk_fp8_f32(a, b, 0, false);   // bytes 0,1
  w = __builtin_amdgcn_cvt_pk_fp8_f32(c, d, w, true);        // bytes 2,3
  return (unsigned int)w;
}

__device__ __forceinline__ float wave_sum(float v) {
  for (int o = 32; o > 0; o >>= 1) v += __shfl_down(v, o, 64);
  return v;
}

// ================= fused prep (R3 layout) ================================================
// [0,4096): prep_x  [4096,4608): prep_w  [4608,4640): prep_wh  [4640,5168): borders
// [5168,5552): zero head_acc
__global__ void prep_fused(const float* __restrict__ x, const float* __restrict__ Wc,
                           const float* __restrict__ Wcls, const float* __restrict__ Wbb,
                           unsigned char* __restrict__ xt, unsigned char* __restrict__ Wa,
                           unsigned short* __restrict__ Wh, float* __restrict__ accbuf,
                           float* __restrict__ head_acc) {
  __shared__ float smem[9216];   // 36 KB shared across branches
  int bid = blockIdx.x, t = threadIdx.x;
  if (bid < 4096) {
    int cx = bid & 7, h = (bid >> 3) & 63, b = bid >> 9;
    float* tile = smem;   // [128][49]
    const float* src = x + ((long)(b * CIN + cx * 128) * H_ + h) * W_;
    for (int it = 0; it < 6; ++it) {
      int e = it * 256 + t;
      int cl = e / 12, w4 = e % 12;
      float4_t v = *(const float4_t*)&src[(long)cl * HW + w4 * 4];
      int base = cl * 49 + w4 * 4;
      tile[base] = v.x; tile[base + 1] = v.y; tile[base + 2] = v.z; tile[base + 3] = v.w;
    }
    __syncthreads();
    unsigned char* dst = xt + ((long)(b * HP + h + 1) * WP + 1) * CIN + cx * 128;
    for (int it = 0; it < 6; ++it) {
      int e = it * 256 + t;
      int w = e >> 5, g = e & 31;
      float v0 = tile[(g * 4 + 0) * 49 + w] * 16.f;
      float v1 = tile[(g * 4 + 1) * 49 + w] * 16.f;
      float v2 = tile[(g * 4 + 2) * 49 + w] * 16.f;
      float v3 = tile[(g * 4 + 3) * 49 + w] * 16.f;
      *(unsigned int*)&dst[(long)w * CIN + g * 4] = pack4_fp8(v0, v1, v2, v3);
    }
  } else if (bid < 4608) {
    int o = bid - 4096;
    float* lw = smem;
    const float* src = Wc + (long)o * K9;
    for (int i = 0; i < 9; ++i)
      *(float4_t*)&lw[i * 1024 + t * 4] = *(const float4_t*)&src[i * 1024 + t * 4];
    __syncthreads();
    unsigned char* dst = Wa + (long)o * K9;
    int c = t * 4;
    for (int off = 0; off < 9; ++off) {
      float v0 = lw[(c + 0) * 9 + off] * 512.f;
      float v1 = lw[(c + 1) * 9 + off] * 512.f;
      float v2 = lw[(c + 2) * 9 + off] * 512.f;
      float v3 = lw[(c + 3) * 9 + off] * 512.f;
      *(unsigned int*)&dst[off * 1024 + c] = pack4_fp8(v0, v1, v2, v3);
    }
  } else if (bid < 4640) {
    int e = (bid - 4608) * 1024 + t * 4;
    int m = e >> 9, c = e & 511;
    float v0 = 0.f, v1 = 0.f, v2 = 0.f, v3 = 0.f;
    if (m < 18) {
      const float* s = Wcls + m * 512 + c;
      v0 = s[0]; v1 = s[1]; v2 = s[2]; v3 = s[3];
    } else if (m < 54) {
      const float* s = Wbb + (m - 18) * 512 + c;
      v0 = s[0]; v1 = s[1]; v2 = s[2]; v3 = s[3];
    }
    ushort4_t pk; pk.x = f2bf(v0); pk.y = f2bf(v1); pk.z = f2bf(v2); pk.w = f2bf(v3);
    *(ushort4_t*)&Wh[e] = pk;
    if (bid == 4608 && t < 4) accbuf[t] = 0.f;   // sums[3] + ticket
  } else if (bid < 5168) {
    int bid2 = bid - 4640;
    int b = bid2 / 66, h = bid2 % 66;
    unsigned char* base = xt + (long)(b * 66 + h) * 50 * 1024;
    int4v z = {};
    if (h == 0 || h == 65) {
      for (int i = t; i < 3200; i += 256) *(int4v*)(base + (long)i * 16) = z;
    } else if (t < 128) {
      int which = t >> 6, off = t & 63;
      *(int4v*)(base + (long)which * 49 * 1024 + (long)off * 16) = z;
    }
  } else {
    long base = (long)(bid - 5168) * 4096 + t * 16;
    float4_t z = {};
    for (int i = 0; i < 4; ++i) *(float4_t*)&head_acc[base + i * 4] = z;
  }
}

// ---------------- main conv GEMM (MX-fp8), NO-LDS K-loop + fused head epilogue -----------
// M=512, N=24576, K=9216. 128x128 tile, K-step 128. grid (192, 4), 256 threads.
// Fragments loaded global->VGPR directly; no barriers in K-loop -> compiler pipelines.
__global__ __launch_bounds__(256, 2)
void conv_gemm(const unsigned char* __restrict__ Wa, const unsigned char* __restrict__ xt,
               const float* __restrict__ bias, const unsigned short* __restrict__ Wh,
               float* __restrict__ head_acc) {
  __shared__ __align__(16) unsigned char sm[32768];   // P-buffer (epilogue only)
  unsigned short* P = (unsigned short*)sm;            // [128 n][128 m] bf16, chunk-swizzled
  int t = threadIdx.x;
  int lane = t & 63, wv = t >> 6;
  int m0 = blockIdx.y * 128;
  int n0 = blockIdx.x * 128;
  int wm = wv >> 1, wn = wv & 1;
  int quad = lane >> 4, col = lane & 15;
  const unsigned char* aRow[4];
  for (int i = 0; i < 4; ++i)
    aRow[i] = Wa + (long)(m0 + wm * 64 + i * 16 + col) * K9 + quad * 32;
  const unsigned char* bRow[4];
  for (int j = 0; j < 4; ++j) {
    int n = n0 + wn * 64 + j * 16 + col;
    int b = n / HW; int rem = n % HW; int h = rem / W_; int w = rem % W_;
    bRow[j] = xt + ((long)(b * HP + h) * WP + w) * CIN + quad * 32;
  }
  float4_t acc[4][4] = {};

  auto loadFrags = [&](int kt, int8v* af, int8v* bf) {
    long aoff = (long)kt * 128;
    int off = kt >> 3;                       // tap
    int dy = off / 3, dx = off % 3;
    long boff = (long)(dy * WP + dx) * CIN + (kt & 7) * 128;
    for (int i = 0; i < 4; ++i) {
      int4v lo = *(const int4v*)(aRow[i] + aoff);
      int4v hi = *(const int4v*)(aRow[i] + aoff + 16);
      af[i] = (int8v){lo.x, lo.y, lo.z, lo.w, hi.x, hi.y, hi.z, hi.w};
    }
    for (int j = 0; j < 4; ++j) {
      int4v lo = *(const int4v*)(bRow[j] + boff);
      int4v hi = *(const int4v*)(bRow[j] + boff + 16);
      bf[j] = (int8v){lo.x, lo.y, lo.z, lo.w, hi.x, hi.y, hi.z, hi.w};
    }
  };

  int8v afc[4], bfc[4];
  loadFrags(0, afc, bfc);
#pragma unroll 2
  for (int kt = 0; kt < 72; ++kt) {
    int8v afn[4], bfn[4];
    if (kt < 71) loadFrags(kt + 1, afn, bfn);
    for (int i = 0; i < 4; ++i)
      for (int j = 0; j < 4; ++j)
        // A=W scaled by 2^9 -> e8m0 118 (2^-9); B=x scaled by 2^4 -> e8m0 123 (2^-4)
        acc[i][j] = __builtin_amdgcn_mfma_scale_f32_16x16x128_f8f6f4(
            afc[i], bfc[j], acc[i][j], 0, 0, 0, 0x76767676, 0, 0x7B7B7B7B);
    for (int i = 0; i < 4; ++i) { afc[i] = afn[i]; bfc[i] = bfn[i]; }
  }

  // ---- epilogue 1: bias + relu -> bf16 into swizzled P[n][m] ----
  __syncthreads();
  for (int i = 0; i < 4; ++i) {
    int mb = m0 + wm * 64 + i * 16 + quad * 4;
    int ml = wm * 64 + i * 16 + quad * 4;
    float b0 = bias[mb + 0], b1 = bias[mb + 1], b2 = bias[mb + 2], b3 = bias[mb + 3];
    int chunk = ml >> 3, sub = ml & 7;
    for (int j = 0; j < 4; ++j) {
      int nl = wn * 64 + j * 16 + col;
      ushort4_t pk;
      pk.x = f2bf(fmaxf(acc[i][j].x + b0, 0.f));
      pk.y = f2bf(fmaxf(acc[i][j].y + b1, 0.f));
      pk.z = f2bf(fmaxf(acc[i][j].z + b2, 0.f));
      pk.w = f2bf(fmaxf(acc[i][j].w + b3, 0.f));
      *(ushort4_t*)((unsigned char*)P + nl * 256 + (((chunk ^ (nl & 15)) << 4) + sub * 2)) = pk;
    }
  }
  __syncthreads();
  // ---- epilogue 2: head partial GEMM -> atomicAdd into head_acc[64][24576] ----
  for (int mt = 0; mt < 4; ++mt) {
    for (int nt = 0; nt < 2; ++nt) {
      int nl = wv * 32 + nt * 16 + col;
      float4_t acc2 = {};
      for (int ks = 0; ks < 4; ++ks) {
        bf16x8 af2 = *(const bf16x8*)&Wh[(mt * 16 + col) * 512 + m0 + ks * 32 + quad * 8];
        int ch = ks * 4 + quad;
        bf16x8 bf2 = *(const bf16x8*)((unsigned char*)P + nl * 256 + ((ch ^ (nl & 15)) << 4));
        acc2 = __builtin_amdgcn_mfma_f32_16x16x32_bf16(af2, bf2, acc2, 0, 0, 0);
      }
      int n = n0 + nl;
      for (int r = 0; r < 4; ++r) {
        int mh = mt * 16 + quad * 4 + r;
        if (mh < 54) atomicAdd(&head_acc[(long)mh * NPOS + n], acc2[r]);
      }
    }
  }
}

// ---------------- fused losses + outputs + finalize --------------------------------------
__global__ void loss_fused(const float* __restrict__ head_acc, const int* __restrict__ label,
                           const float* __restrict__ b_cls, const float* __restrict__ b_bbox,
                           float* __restrict__ prob, float* __restrict__ out_bbox,
                           const float* __restrict__ tgt,
                           const float* __restrict__ iw, const float* __restrict__ ow,
                           float* __restrict__ acc, float* __restrict__ out_scalars) {
  int lane = threadIdx.x & 63, wv = threadIdx.x >> 6;
  __shared__ float red[8];
  if (blockIdx.x < 864) {
    int idx = blockIdx.x * 256 + threadIdx.x;
    int b = idx / 27648; int r = idx % 27648;
    int a = r / HW; int r2 = r % HW;
    long nn = (long)b * HW + r2;
    float x0 = head_acc[(long)a * NPOS + nn] + b_cls[a];
    float x1 = head_acc[(long)(a + 9) * NPOS + nn] + b_cls[a + 9];
    float mx = fmaxf(x0, x1);
    float e0 = __expf(x0 - mx), e1 = __expf(x1 - mx);
    float s = e0 + e1;
    long i0 = (long)(b * 18 + a) * HW + r2;
    prob[i0] = e0 / s;
    prob[i0 + (long)9 * HW] = e1 / s;
    int lb = label[idx];
    float nll = 0.f, val = 0.f;
    if (lb != -1) {
      val = 1.f;
      float xl = (lb > 0) ? x1 : x0;
      nll = -(xl - mx - __logf(s));
    }
    nll = wave_sum(nll);
    val = wave_sum(val);
    if (lane == 0) { red[wv] = nll; red[4 + wv] = val; }
    __syncthreads();
    if (threadIdx.x == 0) {
      atomicAdd(&acc[0], red[0] + red[1] + red[2] + red[3]);
      atomicAdd(&acc[1], red[4] + red[5] + red[6] + red[7]);
    }
  } else {
    int bid = blockIdx.x - 864;
    float s = 0.f;
    const long total = (long)B_ * 36 * HW;   // 884736
    for (long i = (long)bid * 256 + threadIdx.x; i < total; i += (long)1728 * 256) {
      int hw = (int)(i % HW);
      int c = (int)((i / HW) % 36);
      int b = (int)(i / (36 * HW));
      float pv = head_acc[(long)(18 + c) * NPOS + (long)b * HW + hw] + b_bbox[c];
      out_bbox[i] = pv;
      float d = iw[i] * (pv - tgt[i]);
      float ad = fabsf(d);
      float l = (ad < (1.f / 9.f)) ? d * d * 4.5f : ad - (1.f / 18.f);
      s += ow[i] * l;
    }
    s = wave_sum(s);
    if (lane == 0) red[wv] = s;
    __syncthreads();
    if (threadIdx.x == 0) atomicAdd(&acc[2], red[0] + red[1] + red[2] + red[3]);
  }
  if (threadIdx.x == 0) {
    __threadfence();
    float tk = atomicAdd(&acc[3], 1.f);
    if (tk == 2591.f) {
      float c0 = atomicAdd(&acc[0], 0.f);
      float c1 = atomicAdd(&acc[1], 0.f);
      float c2 = atomicAdd(&acc[2], 0.f);
      out_scalars[0] = c0 / fmaxf(c1, 1.f);
      out_scalars[1] = c2 / (float)B_;
    }
  }
}

extern "C" void kernel_launch(void* const* d_in, const int* in_sizes, int n_in,
                              void* d_out, int out_size, void* d_ws, size_t ws_size,
                              hipStream_t stream) {
  const float* base_feat = (const float*)d_in[0];
  const float* W_conv    = (const float*)d_in[1];
  const float* b_conv    = (const float*)d_in[2];
  const float* W_cls     = (const float*)d_in[3];
  const float* b_cls     = (const float*)d_in[4];
  const float* W_bbox    = (const float*)d_in[5];
  const float* b_bbox    = (const float*)d_in[6];
  const int*   rpn_label = (const int*)d_in[7];
  const float* bb_tgt    = (const float*)d_in[8];
  const float* bb_iw     = (const float*)d_in[9];
  const float* bb_ow     = (const float*)d_in[10];

  float* out = (float*)d_out;
  float* out_cls_prob = out;                         // 442368
  float* out_bbox     = out + 442368;                // 884736
  float* out_scalars  = out + 442368 + 884736;       // 2

  size_t off = 0;
  auto alloc = [&](size_t bytes) {
    void* p = (char*)d_ws + off;
    off = (off + bytes + 255) & ~(size_t)255;
    return p;
  };
  const size_t XT_BYTES = (size_t)B_ * HP * WP * CIN;              // 27,033,600 (fp8)
  unsigned char*  xt    = (unsigned char*)alloc(XT_BYTES);
  unsigned char*  Wa    = (unsigned char*)alloc((size_t)OC * K9);
  unsigned short* Wh    = (unsigned short*)alloc((size_t)64 * 512 * 2);
  float* head_acc       = (float*)alloc((size_t)64 * NPOS * 4);    // 6.29 MB
  float* accbuf         = (float*)alloc(16);

  prep_fused<<<5552, 256, 0, stream>>>(base_feat, W_conv, W_cls, W_bbox, xt, Wa, Wh,
                                       accbuf, head_acc);
  conv_gemm<<<dim3(192, 4), 256, 0, stream>>>(Wa, xt, b_conv, Wh, head_acc);
  loss_fused<<<2592, 256, 0, stream>>>(head_acc, rpn_label, b_cls, b_bbox,
                                       out_cls_prob, out_bbox, bb_tgt, bb_iw, bb_ow,
                                       accbuf, out_scalars);
}